// Round 7
// baseline (290.678 us; speedup 1.0000x reference)
//
#include <hip/hip_runtime.h>
#include <hip/hip_cooperative_groups.h>
#include <math.h>

namespace cg = cooperative_groups;

using f4 = __attribute__((ext_vector_type(4))) float;

// Shape (fixed): B=8, S=4096, D=1024, CD=1024
constexpr int Bn = 8;
constexpr int Dn = 1024;
constexpr int TWO_D = 2048;
constexpr int NTHR = 256;
constexpr int NPAIR = 16384;     // 32768 rows as 16384 row-pairs

// ws layout (floats)
constexpr int OFF_PART = 0;      // 2048 partials for |w| reduction
constexpr int OFF_CQ   = 4096;   // 8192: quantized c (8 x 1024)
constexpr int OFF_G    = 16384;  // 8192: rw * (1 + scale)  (8 x 1024)
constexpr int OFF_SH   = 24576;  // 8192: shift (8 x 1024)

__device__ __forceinline__ float wsumf(float v) {
#pragma unroll
    for (int o = 32; o > 0; o >>= 1) v += __shfl_xor(v, o, 64);
    return v;
}
__device__ __forceinline__ float wmaxf(float v) {
#pragma unroll
    for (int o = 32; o > 0; o >>= 1) v = fmaxf(v, __shfl_xor(v, o, 64));
    return v;
}
__device__ __forceinline__ float qclip(float v, float s, float lo, float hi) {
    return fminf(fmaxf(rintf(v * s), lo), hi);
}
__device__ __forceinline__ float maxabs4(f4 v) {
    return fmaxf(fmaxf(fabsf(v.x), fabsf(v.y)), fmaxf(fabsf(v.z), fabsf(v.w)));
}
__device__ __forceinline__ float sumsq4(f4 v) {
    return v.x*v.x + v.y*v.y + v.z*v.z + v.w*v.w;
}

// ---- shared phase bodies -------------------------------------------------

__device__ __forceinline__ void c_quant_block(const float* __restrict__ c,
                                              float* __restrict__ cq, int b) {
    // whole 256-thread block quantizes one c row (1024 floats)
    int tid = threadIdx.x;
    __shared__ float lm[4];
    f4 v = ((const f4*)(c + (size_t)b * Dn))[tid];
    float m = wmaxf(maxabs4(v));
    if ((tid & 63) == 0) lm[tid >> 6] = m;
    __syncthreads();
    float mx = fmaxf(fmaxf(lm[0], lm[1]), fmaxf(lm[2], lm[3]));
    float scl = 127.0f / fmaxf(mx, 1e-5f);
    float inv = 1.0f / scl;
    f4 q;
    q.x = qclip(v.x, scl, -128.f, 127.f) * inv;
    q.y = qclip(v.y, scl, -128.f, 127.f) * inv;
    q.z = qclip(v.z, scl, -128.f, 127.f) * inv;
    q.w = qclip(v.w, scl, -128.f, 127.f) * inv;
    ((f4*)(cq + (size_t)b * Dn))[tid] = q;
}

__device__ __forceinline__ void emb_wave(const float* __restrict__ w,
                                         const float* __restrict__ bp,
                                         const float* __restrict__ cq,
                                         const float* __restrict__ rw,
                                         float mw, int d, int lane,
                                         float* __restrict__ g,
                                         float* __restrict__ sh) {
    float sw = 1.0f / mw;
    const float* wr = w + (size_t)d * Dn + (size_t)lane * 16;
    float t[16];
#pragma unroll
    for (int j = 0; j < 16; j += 4) {
        f4 v = *(const f4*)(wr + j);
        t[j+0] = qclip(v.x, sw, -1.f, 1.f);
        t[j+1] = qclip(v.y, sw, -1.f, 1.f);
        t[j+2] = qclip(v.z, sw, -1.f, 1.f);
        t[j+3] = qclip(v.w, sw, -1.f, 1.f);
    }
    float acc[Bn];
#pragma unroll
    for (int b = 0; b < Bn; ++b) {
        const float* cr = cq + (size_t)b * Dn + (size_t)lane * 16;
        float dot = 0.0f;
#pragma unroll
        for (int j = 0; j < 16; j += 4) {
            f4 u = *(const f4*)(cr + j);
            dot += t[j+0]*u.x + t[j+1]*u.y + t[j+2]*u.z + t[j+3]*u.w;
        }
        acc[b] = dot;
    }
#pragma unroll
    for (int o = 32; o > 0; o >>= 1) {
#pragma unroll
        for (int b = 0; b < Bn; ++b) acc[b] += __shfl_xor(acc[b], o, 64);
    }
    if (lane == 0) {
        float bias = bp[d];
        if (d < Dn) {
            float rwd = rw[d];
#pragma unroll
            for (int b = 0; b < Bn; ++b)
                g[b * Dn + d] = rwd * (1.0f + (acc[b] * mw + bias));
        } else {
#pragma unroll
            for (int b = 0; b < Bn; ++b)
                sh[b * Dn + (d - Dn)] = acc[b] * mw + bias;
        }
    }
}

// process one row-pair (rows 2P, 2P+1) for one wave; nt stores for out
__device__ __forceinline__ void main_pair(const float* __restrict__ x,
                                          const float* __restrict__ g,
                                          const float* __restrict__ sh,
                                          float* __restrict__ out,
                                          int P, int lane) {
    int row = P * 2;
    int b   = row >> 12;
    const f4* xa = (const f4*)(x + (size_t)row * Dn);
    const f4* xb = xa + 256;
    f4 a0 = xa[lane], a1 = xa[lane+64], a2 = xa[lane+128], a3 = xa[lane+192];
    f4 b0 = xb[lane], b1 = xb[lane+64], b2 = xb[lane+128], b3 = xb[lane+192];
    float sa = sumsq4(a0) + sumsq4(a1) + sumsq4(a2) + sumsq4(a3);
    float sb = sumsq4(b0) + sumsq4(b1) + sumsq4(b2) + sumsq4(b3);
#pragma unroll
    for (int o = 32; o > 0; o >>= 1) {
        sa += __shfl_xor(sa, o, 64);
        sb += __shfl_xor(sb, o, 64);
    }
    float ia = rsqrtf(sa * (1.0f / 1024.0f) + 1e-6f);
    float ib = rsqrtf(sb * (1.0f / 1024.0f) + 1e-6f);
    const f4* gv = (const f4*)(g  + (size_t)b * Dn);
    const f4* hv = (const f4*)(sh + (size_t)b * Dn);
    f4* oa = (f4*)(out + (size_t)row * Dn);
    f4* ob = oa + 256;
#pragma unroll
    for (int q = 0; q < 4; ++q) {
        int idx = lane + q * 64;
        f4 va = (q == 0) ? a0 : (q == 1) ? a1 : (q == 2) ? a2 : a3;
        f4 vb = (q == 0) ? b0 : (q == 1) ? b1 : (q == 2) ? b2 : b3;
        f4 gg = gv[idx];
        f4 hh = hv[idx];
        f4 o;
        o.x = va.x * ia * gg.x + hh.x;
        o.y = va.y * ia * gg.y + hh.y;
        o.z = va.z * ia * gg.z + hh.z;
        o.w = va.w * ia * gg.w + hh.w;
        __builtin_nontemporal_store(o, &oa[idx]);
        o.x = vb.x * ib * gg.x + hh.x;
        o.y = vb.y * ib * gg.y + hh.y;
        o.z = vb.z * ib * gg.z + hh.z;
        o.w = vb.w * ib * gg.w + hh.w;
        __builtin_nontemporal_store(o, &ob[idx]);
    }
}

// ---- cooperative fused kernel (grid-stride, any NBLK in [512, 2048]) ----

__global__ void __launch_bounds__(NTHR, 8) k_fused(
    const float* __restrict__ x, const float* __restrict__ c,
    const float* __restrict__ w, const float* __restrict__ bp,
    const float* __restrict__ rw, float* __restrict__ part,
    float* __restrict__ cq, float* __restrict__ g,
    float* __restrict__ sh, float* __restrict__ out)
{
    cg::grid_group grid = cg::this_grid();
    const int tid = threadIdx.x, lane = tid & 63, widx = tid >> 6;
    const int blk = blockIdx.x;
    const int nblk = gridDim.x;
    __shared__ float lds[4];

    // phase 1: |w| partials over 2048 chunks of 1024 floats (grid-stride)
    for (int ch = blk; ch < TWO_D; ch += nblk) {
        f4 v = *(const f4*)(w + (size_t)ch * 1024 + (size_t)tid * 4);
        float s = wsumf(fabsf(v.x) + fabsf(v.y) + fabsf(v.z) + fabsf(v.w));
        if (lane == 0) lds[widx] = s;
        __syncthreads();
        if (tid == 0) part[ch] = lds[0] + lds[1] + lds[2] + lds[3];
        __syncthreads();
    }
    if (blk < Bn) c_quant_block(c, cq, blk);
    grid.sync();

    // phase 2: mw + tiny GEMM (blocks 0..511, one wave per d)
    if (blk < 512) {
        float s = 0.0f;
#pragma unroll
        for (int k = 0; k < 8; ++k) s += part[tid + k * 256];
        s = wsumf(s);
        __syncthreads();
        if (lane == 0) lds[widx] = s;
        __syncthreads();
        float mw = fmaxf((lds[0]+lds[1]+lds[2]+lds[3]) * (1.0f / 2097152.0f), 1e-5f);
        emb_wave(w, bp, cq, rw, mw, blk * 4 + widx, lane, g, sh);
    }
    grid.sync();

    // phase 3: stream x -> out, grid-stride over row-pairs
    {
        int W = blk * 4 + widx;
        int nW = nblk * 4;
        for (int P = W; P < NPAIR; P += nW)
            main_pair(x, g, sh, out, P, lane);
    }
}

// ---- fallback path (proven R5 kernels + nt stores) ----------------------

__global__ void k_pre(const float* __restrict__ w, const float* __restrict__ c,
                      float* __restrict__ part, float* __restrict__ cq) {
    int tid = threadIdx.x;
    if (blockIdx.x < TWO_D) {
        f4 v = *(const f4*)(w + (size_t)blockIdx.x * 1024 + (size_t)tid * 4);
        float s = wsumf(fabsf(v.x) + fabsf(v.y) + fabsf(v.z) + fabsf(v.w));
        __shared__ float lds[4];
        if ((tid & 63) == 0) lds[tid >> 6] = s;
        __syncthreads();
        if (tid == 0) part[blockIdx.x] = lds[0] + lds[1] + lds[2] + lds[3];
    } else {
        c_quant_block(c, cq, blockIdx.x - TWO_D);
    }
}

__global__ void k_emb(const float* __restrict__ w, const float* __restrict__ bp,
                      const float* __restrict__ cq, const float* __restrict__ part,
                      const float* __restrict__ rw,
                      float* __restrict__ g, float* __restrict__ sh) {
    int tid = threadIdx.x;
    float s = 0.0f;
#pragma unroll
    for (int k = 0; k < 8; ++k) s += part[tid + k * 256];
    s = wsumf(s);
    __shared__ float lds[4];
    if ((tid & 63) == 0) lds[tid >> 6] = s;
    __syncthreads();
    float mw = fmaxf((lds[0] + lds[1] + lds[2] + lds[3]) * (1.0f / 2097152.0f), 1e-5f);
    emb_wave(w, bp, cq, rw, mw, (blockIdx.x * blockDim.x + tid) >> 6, tid & 63, g, sh);
}

__global__ void __launch_bounds__(256) k_main(
        const float* __restrict__ x, const float* __restrict__ g,
        const float* __restrict__ sh, float* __restrict__ out) {
    int P = blockIdx.x * 4 + (threadIdx.x >> 6);
    main_pair(x, g, sh, out, P, threadIdx.x & 63);
}

extern "C" void kernel_launch(void* const* d_in, const int* in_sizes, int n_in,
                              void* d_out, int out_size, void* d_ws, size_t ws_size,
                              hipStream_t stream) {
    const float* x  = (const float*)d_in[0];
    const float* c  = (const float*)d_in[1];
    const float* w  = (const float*)d_in[2];
    const float* bp = (const float*)d_in[3];
    const float* rw = (const float*)d_in[4];
    float* outp = (float*)d_out;
    float* ws   = (float*)d_ws;

    float* part = ws + OFF_PART;
    float* cq   = ws + OFF_CQ;
    float* g    = ws + OFF_G;
    float* sh   = ws + OFF_SH;

    // Query runtime co-residency (deterministic, capture-safe host query).
    int perCU = 0;
    hipError_t qerr = hipOccupancyMaxActiveBlocksPerMultiprocessor(
        &perCU, (const void*)k_fused, NTHR, 0);
    int nblk = (qerr == hipSuccess) ? perCU * 256 : 0;   // 256 CUs on MI355X
    if (nblk > 2048) nblk = 2048;

    bool done = false;
    if (nblk >= 512) {
        void* args[] = { (void*)&x, (void*)&c, (void*)&w, (void*)&bp, (void*)&rw,
                         (void*)&part, (void*)&cq, (void*)&g, (void*)&sh, (void*)&outp };
        hipError_t err = hipLaunchCooperativeKernel((const void*)k_fused, dim3(nblk),
                                                    dim3(NTHR), args, 0, stream);
        done = (err == hipSuccess);
    }
    if (!done) {
        k_pre <<<TWO_D + Bn, 256, 0, stream>>>(w, c, part, cq);
        k_emb <<<TWO_D / 4, 256, 0, stream>>>(w, bp, cq, part, rw, g, sh);
        k_main<<<NPAIR / 4, 256, 0, stream>>>(x, g, sh, outp);
    }
}

// Round 8
// 61.042 us; speedup vs baseline: 4.7620x; 4.7620x over previous
//
#include <hip/hip_runtime.h>
#include <math.h>

// Shape (fixed): B=8, S=4096, D=1024, CD=1024
// out = rmsnorm(x) * (1 + scale[b]) + shift[b], [scale|shift] = cq @ wq^T + b_proj
// g[b,d] = rw[d]*(1+scale[b,d]); k_main: out = x*inv*g + sh.

constexpr int Bn = 8;
constexpr int Dn = 1024;
constexpr int TWO_D = 2048;
// ws layout (floats)
constexpr int OFF_PART = 0;      // 2048 partials for |w| reduction
constexpr int OFF_CQ   = 4096;   // 8192: quantized c (8 x 1024)
constexpr int OFF_G    = 16384;  // 8192: rw * (1 + scale)  (8 x 1024)
constexpr int OFF_SH   = 24576;  // 8192: shift (8 x 1024)

using f4 = __attribute__((ext_vector_type(4))) float;

__device__ __forceinline__ float wsumf(float v) {
#pragma unroll
    for (int o = 32; o > 0; o >>= 1) v += __shfl_xor(v, o, 64);
    return v;
}
__device__ __forceinline__ float wmaxf(float v) {
#pragma unroll
    for (int o = 32; o > 0; o >>= 1) v = fmaxf(v, __shfl_xor(v, o, 64));
    return v;
}
__device__ __forceinline__ float qclip(float v, float s, float lo, float hi) {
    return fminf(fmaxf(rintf(v * s), lo), hi);
}
__device__ __forceinline__ float maxabs4(f4 v) {
    return fmaxf(fmaxf(fabsf(v.x), fabsf(v.y)), fmaxf(fabsf(v.z), fabsf(v.w)));
}
__device__ __forceinline__ float sumsq4(f4 v) {
    return v.x*v.x + v.y*v.y + v.z*v.z + v.w*v.w;
}

// 1) fused preamble: blocks 0..2047 -> |w| partials; blocks 2048..2055 -> c-quant
__global__ void k_pre(const float* __restrict__ w, const float* __restrict__ c,
                      float* __restrict__ part, float* __restrict__ cq) {
    int tid = threadIdx.x;
    if (blockIdx.x < TWO_D) {
        f4 v = *(const f4*)(w + (size_t)blockIdx.x * 1024 + (size_t)tid * 4);
        float s = wsumf(fabsf(v.x) + fabsf(v.y) + fabsf(v.z) + fabsf(v.w));
        __shared__ float lds[4];
        if ((tid & 63) == 0) lds[tid >> 6] = s;
        __syncthreads();
        if (tid == 0) part[blockIdx.x] = lds[0] + lds[1] + lds[2] + lds[3];
    } else {
        int b = blockIdx.x - TWO_D;
        f4 v = ((const f4*)(c + (size_t)b * Dn))[tid];
        float m = wmaxf(maxabs4(v));
        __shared__ float lm[4];
        if ((tid & 63) == 0) lm[tid >> 6] = m;
        __syncthreads();
        float mx = fmaxf(fmaxf(lm[0], lm[1]), fmaxf(lm[2], lm[3]));
        float scale = 127.0f / fmaxf(mx, 1e-5f);
        float inv = 1.0f / scale;
        f4 q;
        q.x = qclip(v.x, scale, -128.f, 127.f) * inv;
        q.y = qclip(v.y, scale, -128.f, 127.f) * inv;
        q.z = qclip(v.z, scale, -128.f, 127.f) * inv;
        q.w = qclip(v.w, scale, -128.f, 127.f) * inv;
        ((f4*)(cq + (size_t)b * Dn))[tid] = q;
    }
}

// 2) tiny GEMM: one wave per output row d; 8 batch dots in regs, one
//    interleaved butterfly. Writes g = rw*(1+scale) and sh = shift.
__global__ void k_emb(const float* __restrict__ w, const float* __restrict__ bp,
                      const float* __restrict__ cq, const float* __restrict__ part,
                      const float* __restrict__ rw,
                      float* __restrict__ g, float* __restrict__ sh) {
    int tid = threadIdx.x;
    float s = 0.0f;
#pragma unroll
    for (int k = 0; k < 8; ++k) s += part[tid + k * 256];
    s = wsumf(s);
    __shared__ float lds[4];
    if ((tid & 63) == 0) lds[tid >> 6] = s;
    __syncthreads();
    float mw = fmaxf((lds[0] + lds[1] + lds[2] + lds[3]) * (1.0f / 2097152.0f), 1e-5f);
    float sw = 1.0f / mw;

    int lane = tid & 63;
    int d = (blockIdx.x * blockDim.x + tid) >> 6;   // 0..2047
    const float* wr = w + (size_t)d * 1024 + (size_t)lane * 16;
    float t[16];
#pragma unroll
    for (int j = 0; j < 16; j += 4) {
        f4 v = *(const f4*)(wr + j);
        t[j + 0] = qclip(v.x, sw, -1.f, 1.f);
        t[j + 1] = qclip(v.y, sw, -1.f, 1.f);
        t[j + 2] = qclip(v.z, sw, -1.f, 1.f);
        t[j + 3] = qclip(v.w, sw, -1.f, 1.f);
    }
    float acc[Bn];
#pragma unroll
    for (int b = 0; b < Bn; ++b) {
        const float* cr = cq + (size_t)b * Dn + (size_t)lane * 16;
        float dot = 0.0f;
#pragma unroll
        for (int j = 0; j < 16; j += 4) {
            f4 u = *(const f4*)(cr + j);
            dot += t[j + 0] * u.x + t[j + 1] * u.y + t[j + 2] * u.z + t[j + 3] * u.w;
        }
        acc[b] = dot;
    }
#pragma unroll
    for (int o = 32; o > 0; o >>= 1) {
#pragma unroll
        for (int b = 0; b < Bn; ++b) acc[b] += __shfl_xor(acc[b], o, 64);
    }
    if (lane == 0) {
        float bias = bp[d];
        if (d < Dn) {
            float rwd = rw[d];
#pragma unroll
            for (int b = 0; b < Bn; ++b)
                g[b * Dn + d] = rwd * (1.0f + (acc[b] * mw + bias));
        } else {
#pragma unroll
            for (int b = 0; b < Bn; ++b)
                sh[b * Dn + (d - Dn)] = acc[b] * mw + bias;
        }
    }
}

// 3) main fused pass: 2048 blocks x 4 waves; each wave owns 4 contiguous rows
//    (2 row-pairs, same batch). g/h loaded ONCE per wave, reused across both
//    pairs. Plain stores (nt stores proven toxic in R7).
__global__ void __launch_bounds__(256) k_main(
        const float* __restrict__ x, const float* __restrict__ g,
        const float* __restrict__ sh, float* __restrict__ out) {
    int tid  = threadIdx.x;
    int lane = tid & 63;
    int row0 = (blockIdx.x * 4 + (tid >> 6)) * 4;   // 4 rows per wave
    int b    = row0 >> 12;

    const f4* gv = (const f4*)(g  + (size_t)b * Dn);
    const f4* hv = (const f4*)(sh + (size_t)b * Dn);
    f4 g0 = gv[lane], g1 = gv[lane+64], g2 = gv[lane+128], g3 = gv[lane+192];
    f4 h0 = hv[lane], h1 = hv[lane+64], h2 = hv[lane+128], h3 = hv[lane+192];

#pragma unroll
    for (int p = 0; p < 2; ++p) {
        int row = row0 + p * 2;
        const f4* xa = (const f4*)(x + (size_t)row * Dn);
        const f4* xb = xa + 256;
        f4 a0 = xa[lane], a1 = xa[lane+64], a2 = xa[lane+128], a3 = xa[lane+192];
        f4 b0 = xb[lane], b1 = xb[lane+64], b2 = xb[lane+128], b3 = xb[lane+192];
        float sa = sumsq4(a0) + sumsq4(a1) + sumsq4(a2) + sumsq4(a3);
        float sb = sumsq4(b0) + sumsq4(b1) + sumsq4(b2) + sumsq4(b3);
#pragma unroll
        for (int o = 32; o > 0; o >>= 1) {
            sa += __shfl_xor(sa, o, 64);
            sb += __shfl_xor(sb, o, 64);
        }
        float ia = rsqrtf(sa * (1.0f / 1024.0f) + 1e-6f);
        float ib = rsqrtf(sb * (1.0f / 1024.0f) + 1e-6f);
        f4* oa = (f4*)(out + (size_t)row * Dn);
        f4* ob = oa + 256;
        f4 o0;
        o0.x = a0.x*ia*g0.x + h0.x; o0.y = a0.y*ia*g0.y + h0.y;
        o0.z = a0.z*ia*g0.z + h0.z; o0.w = a0.w*ia*g0.w + h0.w;
        oa[lane] = o0;
        o0.x = a1.x*ia*g1.x + h1.x; o0.y = a1.y*ia*g1.y + h1.y;
        o0.z = a1.z*ia*g1.z + h1.z; o0.w = a1.w*ia*g1.w + h1.w;
        oa[lane+64] = o0;
        o0.x = a2.x*ia*g2.x + h2.x; o0.y = a2.y*ia*g2.y + h2.y;
        o0.z = a2.z*ia*g2.z + h2.z; o0.w = a2.w*ia*g2.w + h2.w;
        oa[lane+128] = o0;
        o0.x = a3.x*ia*g3.x + h3.x; o0.y = a3.y*ia*g3.y + h3.y;
        o0.z = a3.z*ia*g3.z + h3.z; o0.w = a3.w*ia*g3.w + h3.w;
        oa[lane+192] = o0;
        o0.x = b0.x*ib*g0.x + h0.x; o0.y = b0.y*ib*g0.y + h0.y;
        o0.z = b0.z*ib*g0.z + h0.z; o0.w = b0.w*ib*g0.w + h0.w;
        ob[lane] = o0;
        o0.x = b1.x*ib*g1.x + h1.x; o0.y = b1.y*ib*g1.y + h1.y;
        o0.z = b1.z*ib*g1.z + h1.z; o0.w = b1.w*ib*g1.w + h1.w;
        ob[lane+64] = o0;
        o0.x = b2.x*ib*g2.x + h2.x; o0.y = b2.y*ib*g2.y + h2.y;
        o0.z = b2.z*ib*g2.z + h2.z; o0.w = b2.w*ib*g2.w + h2.w;
        ob[lane+128] = o0;
        o0.x = b3.x*ib*g3.x + h3.x; o0.y = b3.y*ib*g3.y + h3.y;
        o0.z = b3.z*ib*g3.z + h3.z; o0.w = b3.w*ib*g3.w + h3.w;
        ob[lane+192] = o0;
    }
}

extern "C" void kernel_launch(void* const* d_in, const int* in_sizes, int n_in,
                              void* d_out, int out_size, void* d_ws, size_t ws_size,
                              hipStream_t stream) {
    const float* x  = (const float*)d_in[0];
    const float* c  = (const float*)d_in[1];
    const float* w  = (const float*)d_in[2];
    const float* bp = (const float*)d_in[3];
    const float* rw = (const float*)d_in[4];
    float* out = (float*)d_out;
    float* ws  = (float*)d_ws;

    float* part = ws + OFF_PART;
    float* cq   = ws + OFF_CQ;
    float* g    = ws + OFF_G;
    float* sh   = ws + OFF_SH;

    k_pre <<<TWO_D + Bn, 256, 0, stream>>>(w, c, part, cq);
    k_emb <<<TWO_D / 4, 256, 0, stream>>>(w, bp, cq, part, rw, g, sh);
    k_main<<<2048, 256, 0, stream>>>(x, g, sh, out);
}